// Round 2
// baseline (27.332 us; speedup 1.0000x reference)
//
#include <hip/hip_runtime.h>

#define BB 32
#define NN 256
#define DD 32
#define HH 64
#define ET 64    // edge tile (i and j dims)
#define EPAD 68  // LDS row stride (floats): 16B aligned, (68 mod 32)=4 -> <=2-way conflicts
#define WPAD 65

__device__ __forceinline__ float sigmoidf_fast(float v) {
    return 1.0f / (1.0f + __expf(-v));
}

// Kernel 1: Ai[b,n,h] = sum_d x[b,n,d]*W1[h,d];  Ajb[b,n,h] = sum_d x[b,n,d]*W1[h,32+d] + b1[h]
// 16 node rows per block, grid = 8192/16 = 512.
__global__ __launch_bounds__(256) void prep_kernel(const float* __restrict__ x, const float* __restrict__ W1,
                                                   const float* __restrict__ b1,
                                                   float* __restrict__ Ai, float* __restrict__ Ajb)
{
    __shared__ float sWt[64][WPAD];   // W1 transposed: sWt[d][h]
    __shared__ float sx[16][DD + 4];  // +4 pad: conflict-free float4 writes
    __shared__ float sb1[HH];
    const int tid = threadIdx.x;
    for (int k = tid; k < HH * 2 * DD; k += 256) {
        int h = k >> 6, dc = k & 63;
        sWt[dc][h] = W1[k];
    }
    const int rowBase = blockIdx.x * 16;
    if (tid < 128) {
        int row = tid >> 3, c4 = (tid & 7) << 2;
        *(float4*)&sx[row][c4] = *(const float4*)&x[((size_t)rowBase + row) * DD + c4];
    }
    if (tid < HH) sb1[tid] = b1[tid];
    __syncthreads();
#pragma unroll
    for (int q = 0; q < 4; ++q) {
        int item = tid + 256 * q;          // 16 rows x 64 h = 1024 items
        int r = item >> 6, h = item & 63;
        float a0 = 0.f, a1 = sb1[h];
#pragma unroll
        for (int d = 0; d < DD; ++d) {
            float xv = sx[r][d];            // wave-uniform broadcast
            a0 = fmaf(xv, sWt[d][h], a0);   // banks (d+h)%32: 2-way, free
            a1 = fmaf(xv, sWt[d + 32][h], a1);
        }
        size_t o = ((size_t)rowBase + r) * HH + h;
        Ai[o] = a0;
        Ajb[o] = a1;
    }
}

// Kernel 2: 64x64 output tile per block; 4x4 outputs per thread.
// Per 4-h chunk: 9 ds_read_b128 feed 192 VALU ops -> VALU-bound.
__global__ __launch_bounds__(256) void edge_kernel(const float* __restrict__ Ai, const float* __restrict__ Ajb,
                                                   const float* __restrict__ W2, const float* __restrict__ b2,
                                                   float* __restrict__ out)
{
    __shared__ float sAi[ET][EPAD];
    __shared__ float sAj[ET][EPAD];
    __shared__ float sW2[HH];
    const int blk = blockIdx.x;
    const int jt = blk & 3;
    const int it = (blk >> 2) & 3;
    const int b  = blk >> 4;
    const float* aiB = Ai  + ((size_t)b * NN + (size_t)it * ET) * HH;
    const float* ajB = Ajb + ((size_t)b * NN + (size_t)jt * ET) * HH;
    const int tid = threadIdx.x;
    // 64 rows x 16 float4 per tile = 1024 float4; 256 threads -> 4 each per tile
    for (int k = tid; k < ET * HH / 4; k += 256) {
        int row = k >> 4, c4 = (k & 15) << 2;
        *(float4*)&sAi[row][c4] = *(const float4*)&aiB[row * HH + c4];
        *(float4*)&sAj[row][c4] = *(const float4*)&ajB[row * HH + c4];
    }
    if (tid < HH / 4) ((float4*)sW2)[tid] = ((const float4*)W2)[tid];
    __syncthreads();

    const int jl = tid & 15;   // fast dim -> coalesced stores
    const int il = tid >> 4;
    float acc[4][4] = {};      // statically indexed after full unroll
#pragma unroll 4
    for (int h = 0; h < HH; h += 4) {
        float4 w = *(const float4*)&sW2[h];   // uniform broadcast
        float4 ai[4], aj[4];
#pragma unroll
        for (int r = 0; r < 4; ++r) ai[r] = *(const float4*)&sAi[il + 16 * r][h];  // 4 rows, bcast x16
#pragma unroll
        for (int c = 0; c < 4; ++c) aj[c] = *(const float4*)&sAj[jl + 16 * c][h];  // 2-way max, free
#pragma unroll
        for (int r = 0; r < 4; ++r)
#pragma unroll
            for (int c = 0; c < 4; ++c) {
                acc[r][c] += fmaxf(ai[r].x + aj[c].x, 0.f) * w.x;
                acc[r][c] += fmaxf(ai[r].y + aj[c].y, 0.f) * w.y;
                acc[r][c] += fmaxf(ai[r].z + aj[c].z, 0.f) * w.z;
                acc[r][c] += fmaxf(ai[r].w + aj[c].w, 0.f) * w.w;
            }
    }
    const float b2v = b2[0];
    size_t base = ((size_t)b * NN + (size_t)it * ET + il) * NN + (size_t)jt * ET + jl;
#pragma unroll
    for (int r = 0; r < 4; ++r)
#pragma unroll
        for (int c = 0; c < 4; ++c)
            out[base + (size_t)(16 * r) * NN + 16 * c] = sigmoidf_fast(acc[r][c] + b2v);
}

// Fallback: fully fused (only if d_ws too small for Ai/Ajb). 32x32 tiles.
#define FT 32
#define FPAD 68
__global__ __launch_bounds__(256) void fused_kernel(const float* __restrict__ x, const float* __restrict__ W1,
                                                    const float* __restrict__ b1, const float* __restrict__ W2,
                                                    const float* __restrict__ b2, float* __restrict__ out)
{
    __shared__ float sAi[FT][FPAD];
    __shared__ float sAj[FT][FPAD];
    __shared__ float sWt[64][WPAD];
    __shared__ float sxi[FT][DD + 1];
    __shared__ float sxj[FT][DD + 1];
    __shared__ float sW2[HH];
    __shared__ float sb1[HH];
    const int blk = blockIdx.x;
    const int jt = blk & 7;
    const int it = (blk >> 3) & 7;
    const int b  = blk >> 6;
    const int tid = threadIdx.x;
    for (int k = tid; k < HH * 2 * DD; k += 256) {
        int h = k >> 6, dc = k & 63;
        sWt[dc][h] = W1[k];
    }
    const float* xi = x + ((size_t)b * NN + (size_t)it * FT) * DD;
    const float* xj = x + ((size_t)b * NN + (size_t)jt * FT) * DD;
    for (int k = tid; k < FT * DD; k += 256) {
        sxi[k >> 5][k & 31] = xi[k];
        sxj[k >> 5][k & 31] = xj[k];
    }
    if (tid < HH) { sW2[tid] = W2[tid]; sb1[tid] = b1[tid]; }
    __syncthreads();
    for (int k = tid; k < FT * HH; k += 256) {
        int row = k >> 6, h = k & 63;
        float a0 = 0.f, a1 = sb1[h];
#pragma unroll
        for (int d = 0; d < DD; ++d) {
            a0 = fmaf(sxi[row][d], sWt[d][h], a0);
            a1 = fmaf(sxj[row][d], sWt[d + 32][h], a1);
        }
        sAi[row][h] = a0;
        sAj[row][h] = a1;
    }
    __syncthreads();
    const int jl = tid & 15;
    const int il = tid >> 4;
    float acc00 = 0.f, acc01 = 0.f, acc10 = 0.f, acc11 = 0.f;
#pragma unroll
    for (int h = 0; h < HH; h += 4) {
        float4 ai0 = *(const float4*)&sAi[il][h];
        float4 ai1 = *(const float4*)&sAi[il + 16][h];
        float4 aj0 = *(const float4*)&sAj[jl][h];
        float4 aj1 = *(const float4*)&sAj[jl + 16][h];
        float4 w   = *(const float4*)&sW2[h];
        acc00 += fmaxf(ai0.x + aj0.x, 0.f) * w.x;
        acc01 += fmaxf(ai0.x + aj1.x, 0.f) * w.x;
        acc10 += fmaxf(ai1.x + aj0.x, 0.f) * w.x;
        acc11 += fmaxf(ai1.x + aj1.x, 0.f) * w.x;
        acc00 += fmaxf(ai0.y + aj0.y, 0.f) * w.y;
        acc01 += fmaxf(ai0.y + aj1.y, 0.f) * w.y;
        acc10 += fmaxf(ai1.y + aj0.y, 0.f) * w.y;
        acc11 += fmaxf(ai1.y + aj1.y, 0.f) * w.y;
        acc00 += fmaxf(ai0.z + aj0.z, 0.f) * w.z;
        acc01 += fmaxf(ai0.z + aj1.z, 0.f) * w.z;
        acc10 += fmaxf(ai1.z + aj0.z, 0.f) * w.z;
        acc11 += fmaxf(ai1.z + aj1.z, 0.f) * w.z;
        acc00 += fmaxf(ai0.w + aj0.w, 0.f) * w.w;
        acc01 += fmaxf(ai0.w + aj1.w, 0.f) * w.w;
        acc10 += fmaxf(ai1.w + aj0.w, 0.f) * w.w;
        acc11 += fmaxf(ai1.w + aj1.w, 0.f) * w.w;
    }
    const float b2v = b2[0];
    size_t base = ((size_t)b * NN + (size_t)it * FT + il) * NN + (size_t)jt * FT + jl;
    out[base]                = sigmoidf_fast(acc00 + b2v);
    out[base + 16]           = sigmoidf_fast(acc01 + b2v);
    out[base + 16 * NN]      = sigmoidf_fast(acc10 + b2v);
    out[base + 16 * NN + 16] = sigmoidf_fast(acc11 + b2v);
}

extern "C" void kernel_launch(void* const* d_in, const int* in_sizes, int n_in,
                              void* d_out, int out_size, void* d_ws, size_t ws_size,
                              hipStream_t stream) {
    const float* x  = (const float*)d_in[0];
    const float* W1 = (const float*)d_in[1];
    const float* b1 = (const float*)d_in[2];
    const float* W2 = (const float*)d_in[3];
    const float* b2 = (const float*)d_in[4];
    float* out = (float*)d_out;

    const size_t rows = (size_t)BB * NN;                // 8192
    const size_t need = rows * HH * 2 * sizeof(float);  // 4 MB

    if (ws_size >= need) {
        float* Ai  = (float*)d_ws;
        float* Ajb = Ai + rows * HH;
        prep_kernel<<<(int)(rows / 16), 256, 0, stream>>>(x, W1, b1, Ai, Ajb);
        edge_kernel<<<BB * (NN / ET) * (NN / ET), 256, 0, stream>>>(Ai, Ajb, W2, b2, out);
    } else {
        fused_kernel<<<BB * (NN / FT) * (NN / FT), 256, 0, stream>>>(x, W1, b1, W2, b2, out);
    }
}